// Round 12
// baseline (836.624 us; speedup 1.0000x reference)
//
#include <hip/hip_runtime.h>
#include <math.h>

#define CC 128   // channels
// B=16, N=128 per graph, BN=2048 nodes, L=3 layers
// Edge kernel: MFMA split-bf16 (3-term), two-pass wave-local m staging
// (one 32KB LDS plane time-shared hi->lo) -> 39,424 B LDS -> 4 blocks/CU.

typedef float  f32x4  __attribute__((ext_vector_type(4)));
typedef short  s16x8  __attribute__((ext_vector_type(8)));
typedef __bf16 bf16x8 __attribute__((ext_vector_type(8)));

__device__ __forceinline__ float fsilu(float x) { return x / (1.0f + __expf(-x)); }
__device__ __forceinline__ float fsigm(float x) { return 1.0f / (1.0f + __expf(-x)); }
__device__ __forceinline__ float ftanh_(float x) { return 1.0f - 2.0f / (__expf(2.0f * x) + 1.0f); }

// Split fp32 -> bf16 hi + bf16 lo (RNE both). x ~= hi + lo with ~2^-16 rel err.
__device__ __forceinline__ void bsplit(float x, short& hi, short& lo) {
    unsigned xu = __float_as_uint(x);
    unsigned hr = (xu + 0x7FFFu + ((xu >> 16) & 1u)) & 0xFFFF0000u;
    float hf = __uint_as_float(hr);
    float r = x - hf;
    unsigned ru = __float_as_uint(r);
    unsigned lr = ru + 0x7FFFu + ((ru >> 16) & 1u);
    hi = (short)(hr >> 16);
    lo = (short)(lr >> 16);
}

__device__ __forceinline__ f32x4 mfma16(s16x8 a, s16x8 b, f32x4 c) {
    return __builtin_amdgcn_mfma_f32_16x16x32_bf16(
        __builtin_bit_cast(bf16x8, a), __builtin_bit_cast(bf16x8, b), c, 0, 0, 0);
}

// ---------------------------------------------------------------- init ------
__global__ __launch_bounds__(128) void egnn_init(
    const float* __restrict__ t, const float* __restrict__ x,
    const int* __restrict__ atomt, const int* __restrict__ aapos,
    const int* __restrict__ aatype, const int* __restrict__ slen,
    const float* __restrict__ nmask, const float* __restrict__ embW,
    const float* __restrict__ embB, float* __restrict__ h,
    float* __restrict__ xf, float* __restrict__ xA)
{
    const int n = blockIdx.x;
    const int c = threadIdx.x;
    const int b = n >> 7;
    const int i = n & 127;
    const float mi = nmask[n];
    int ia = atomt[n] - 1; if (ia < 0) ia = 0;
    int ip = aapos[n] - 1; if (ip < 0) ip = 0;
    int iq = aatype[n] - 1; if (iq < 0) iq = 0;
    int is = slen[b] - 5;  if (is < 0) is = 0;
    const float tt = t[b] * mi;
    float v = mi * (embW[ia * CC + c] + embW[(54 + ip) * CC + c] +
                    embW[(84 + iq) * CC + c] + embW[(104 + is) * CC + c]) +
              tt * embW[130 * CC + c] + embB[c];
    h[(size_t)n * CC + c] = v;
    if (c < 3) {
        float xv = x[b * 384 + i * 3 + c] * mi;
        xf[3 * n + c] = xv;
        xA[3 * n + c] = xv;
    }
}

// ------------------------------------------------------- weight prep --------
__global__ __launch_bounds__(128) void egnn_wtprep(
    const float* __restrict__ We2, const float* __restrict__ Wc1,
    short* __restrict__ wt)
{
    const int blk = blockIdx.x;          // 96 = 3 layers x 2 mats x 16 chunks
    const int l = blk >> 5;
    const int mat = (blk >> 4) & 1;
    const int chunk = blk & 15;
    const int k = threadIdx.x;
    const float* W = (mat == 0 ? We2 : Wc1) + (size_t)l * CC * CC;
    short* hi = wt + (size_t)(l * 2 + mat) * 32768;
    short* lo = hi + 16384;
#pragma unroll
    for (int nn = 0; nn < 8; ++nn) {
        const int n = chunk * 8 + nn;
        short h_, l_;
        bsplit(W[k * CC + n], h_, l_);
        hi[n * CC + k] = h_;
        lo[n * CC + k] = l_;
    }
}

// ---------------------------------------------------------------- P,Q -------
__global__ __launch_bounds__(128) void egnn_pq(
    const float* __restrict__ h, const float* __restrict__ We1,
    const float* __restrict__ be1, float* __restrict__ P, float* __restrict__ Q)
{
    __shared__ float hs[2][CC];
    const int c = threadIdx.x;
    const int n0 = blockIdx.x * 2;
    hs[0][c] = h[(size_t)n0 * CC + c];
    hs[1][c] = h[(size_t)(n0 + 1) * CC + c];
    __syncthreads();
    const float bv = be1[c];
    float p0 = bv, p1 = bv, q0 = 0.f, q1 = 0.f;
#pragma unroll 4
    for (int k = 0; k < CC; ++k) {
        const float wr = We1[k * CC + c];
        const float wc = We1[(CC + k) * CC + c];
        p0 = fmaf(hs[0][k], wr, p0); p1 = fmaf(hs[1][k], wr, p1);
        q0 = fmaf(hs[0][k], wc, q0); q1 = fmaf(hs[1][k], wc, q1);
    }
    P[(size_t)n0 * CC + c] = p0; P[(size_t)(n0 + 1) * CC + c] = p1;
    Q[(size_t)n0 * CC + c] = q0; Q[(size_t)(n0 + 1) * CC + c] = q1;
}

// ---------------------------------------------------------------- edge ------
// One block per (graph b, row i): 128 edges (i,j). 256 thr = 4 waves.
// Wave w owns j-strip [32w, 32w+32). LDS: one 32KB m-plane (two-pass hi/lo,
// wave-local rows -> no barrier) + 6.5KB floats with phase-A consts overlaid
// by aggp/trp (guarded by one barrier after phase A).
__global__ __launch_bounds__(256, 4) void egnn_edge(
    const float* __restrict__ P, const float* __restrict__ Q,
    const float* __restrict__ xcur, const float* __restrict__ xf,
    const float* __restrict__ nmask, const float* __restrict__ We1t,
    const short* __restrict__ w1hiP, const short* __restrict__ w2hiP,
    const float* __restrict__ be2, const float* __restrict__ Wa,
    const float* __restrict__ ba, const float* __restrict__ bc1,
    const float* __restrict__ Wc2,
    float* __restrict__ xnext, float* __restrict__ agg)
{
    extern __shared__ char smraw[];
    short* ms    = (short*)smraw;         // 128x128 shorts (swizzled), 32KB
    float* fb    = (float*)(ms + 16384);
    float* diffs = fb;                    // 384  (live whole kernel)
    float* emks  = fb + 384;              // 128  (live: ep1)
    float* wass  = fb + 512;              // 128
    float* wc2s  = fb + 640;              // 128
    float* be2s  = fb + 768;              // 128
    float* bc1s  = fb + 896;              // 128
    float* ovl   = fb + 1024;             // 640-float overlay region
    float* rjs   = ovl;                   // 128 (phase A only)
    float* eas   = ovl + 128;             // 128 (phase A only)
    float* pis   = ovl + 256;             // 128 (phase A only)
    float* wrads = ovl + 384;             // 128 (phase A only)
    float* weas  = ovl + 512;             // 128 (phase A only)
    float* aggp  = ovl;                   // 512 (after phase-A barrier)
    float* trp   = ovl + 512;             // 64  (after phase-A barrier)
    // total 32768 + 1664*4 = 39,424 B -> 4 blocks/CU

    const int tid = threadIdx.x;
    const int w  = tid >> 6;
    const int lane = tid & 63;
    const int g  = lane >> 4;            // 0..3
    const int lj = lane & 15;            // 0..15
    const int n = blockIdx.x;
    const int b = n >> 7;
    const int i = n & 127;
    const int nb = b << 7;
    const float mi = nmask[n];

    const short* w1lo = w1hiP + 16384;
    const short* w2lo = w2hiP + 16384;

    if (tid < 128) {
        const int j = tid;
        const float xi0 = xcur[3 * n], xi1 = xcur[3 * n + 1], xi2 = xcur[3 * n + 2];
        const float xj0 = xcur[3 * (nb + j)], xj1 = xcur[3 * (nb + j) + 1], xj2 = xcur[3 * (nb + j) + 2];
        const float d0 = xi0 - xj0, d1 = xi1 - xj1, d2 = xi2 - xj2;
        diffs[3 * j] = d0; diffs[3 * j + 1] = d1; diffs[3 * j + 2] = d2;
        rjs[j] = d0 * d0 + d1 * d1 + d2 * d2;
        const float f0 = xf[3 * n] - xf[3 * (nb + j)];
        const float f1 = xf[3 * n + 1] - xf[3 * (nb + j) + 1];
        const float f2 = xf[3 * n + 2] - xf[3 * (nb + j) + 2];
        eas[j] = f0 * f0 + f1 * f1 + f2 * f2;
        emks[j] = mi * nmask[nb + j] * ((j == i) ? 0.0f : 1.0f);
    } else {
        const int c = tid - 128;
        pis[c]   = P[(size_t)n * CC + c];
        wrads[c] = We1t[c];
        weas[c]  = We1t[CC + c];
        wass[c]  = Wa[c];
        wc2s[c]  = Wc2[c];
        be2s[c]  = be2[c];
        bc1s[c]  = bc1[c];
    }
    __syncthreads();

    // ---- Phase A: M1 computed directly into A-fragment registers ----------
    s16x8 ahi[2][4], alo[2][4];
#pragma unroll
    for (int mt = 0; mt < 2; ++mt) {
        const int j = (w << 5) + (mt << 4) + lj;
        const float r  = rjs[j];
        const float ea = eas[j];
        const float* Qj = Q + (size_t)(nb + j) * CC;
#pragma unroll
        for (int kt = 0; kt < 4; ++kt) {
            const int c0 = (kt << 5) + (g << 3);
            const float4 q0 = *reinterpret_cast<const float4*>(Qj + c0);
            const float4 q1 = *reinterpret_cast<const float4*>(Qj + c0 + 4);
            const float4 p0 = *reinterpret_cast<const float4*>(pis + c0);
            const float4 p1 = *reinterpret_cast<const float4*>(pis + c0 + 4);
            const float4 r0 = *reinterpret_cast<const float4*>(wrads + c0);
            const float4 r1 = *reinterpret_cast<const float4*>(wrads + c0 + 4);
            const float4 e0 = *reinterpret_cast<const float4*>(weas + c0);
            const float4 e1 = *reinterpret_cast<const float4*>(weas + c0 + 4);
            float vv[8];
            vv[0] = fsilu(p0.x + q0.x + r * r0.x + ea * e0.x);
            vv[1] = fsilu(p0.y + q0.y + r * r0.y + ea * e0.y);
            vv[2] = fsilu(p0.z + q0.z + r * r0.z + ea * e0.z);
            vv[3] = fsilu(p0.w + q0.w + r * r0.w + ea * e0.w);
            vv[4] = fsilu(p1.x + q1.x + r * r1.x + ea * e1.x);
            vv[5] = fsilu(p1.y + q1.y + r * r1.y + ea * e1.y);
            vv[6] = fsilu(p1.z + q1.z + r * r1.z + ea * e1.z);
            vv[7] = fsilu(p1.w + q1.w + r * r1.w + ea * e1.w);
#pragma unroll
            for (int e = 0; e < 8; ++e) {
                short h_, l_;
                bsplit(vv[e], h_, l_);
                ahi[mt][kt][e] = h_;
                alo[mt][kt][e] = l_;
            }
        }
    }
    // Overlay guard: all phase-A reads of rjs/eas/pis/wrads/weas are done in
    // every wave before any wave writes aggp/trp (same LDS words).
    __syncthreads();

    // ---- gemm1: acc[mt][nt] = M1 @ We2 (3-term split) ---------------------
    f32x4 acc[2][8];
#pragma unroll
    for (int mt = 0; mt < 2; ++mt)
#pragma unroll
        for (int nt = 0; nt < 8; ++nt) acc[mt][nt] = (f32x4){0.f, 0.f, 0.f, 0.f};
#pragma unroll
    for (int kt = 0; kt < 4; ++kt) {
#pragma unroll
        for (int nt = 0; nt < 8; ++nt) {
            const int wo = ((nt << 4) + lj) * CC + (kt << 5) + (g << 3);
            const s16x8 bh = *reinterpret_cast<const s16x8*>(w1hiP + wo);
            const s16x8 bl = *reinterpret_cast<const s16x8*>(w1lo + wo);
#pragma unroll
            for (int mt = 0; mt < 2; ++mt) {
                acc[mt][nt] = mfma16(ahi[mt][kt], bh, acc[mt][nt]);
                acc[mt][nt] = mfma16(ahi[mt][kt], bl, acc[mt][nt]);
                acc[mt][nt] = mfma16(alo[mt][kt], bh, acc[mt][nt]);
            }
        }
    }

    // ---- epilogue 1: silu + attention gate + agg partials -----------------
    // D-frag: row j = 32w+16mt+4g+r, col c = 16nt+lj.
    float pa[2][4];
#pragma unroll
    for (int mt = 0; mt < 2; ++mt)
#pragma unroll
        for (int r = 0; r < 4; ++r) pa[mt][r] = 0.f;
#pragma unroll
    for (int mt = 0; mt < 2; ++mt)
#pragma unroll
        for (int nt = 0; nt < 8; ++nt) {
            const int c = (nt << 4) + lj;
            const float be = be2s[c], wa = wass[c];
#pragma unroll
            for (int r = 0; r < 4; ++r) {
                const float v = fsilu(acc[mt][nt][r] + be);
                acc[mt][nt][r] = v;
                pa[mt][r] = fmaf(v, wa, pa[mt][r]);
            }
        }
#pragma unroll
    for (int o = 1; o < 16; o <<= 1)
#pragma unroll
        for (int mt = 0; mt < 2; ++mt)
#pragma unroll
            for (int r = 0; r < 4; ++r) pa[mt][r] += __shfl_xor(pa[mt][r], o, 64);
    const float bav = ba[0];
    float gate[2][4];
#pragma unroll
    for (int mt = 0; mt < 2; ++mt)
#pragma unroll
        for (int r = 0; r < 4; ++r) {
            const int j = (w << 5) + (mt << 4) + (g << 2) + r;
            gate[mt][r] = fsigm(pa[mt][r] + bav) * emks[j];
        }

    // ---- two-pass wave-local m staging + gemm2 A-fragment loads -----------
    // Per m-tile: write hi -> read a2h -> write lo (same words) -> read a2l.
    // Rows are wave-private; intra-wave LDS dependency ordering suffices.
    float ap[8];
#pragma unroll
    for (int nt = 0; nt < 8; ++nt) ap[nt] = 0.f;
    s16x8 a2h[2][4], a2l[2][4];
#pragma unroll
    for (int mt = 0; mt < 2; ++mt) {
        short llo[8][4];
#pragma unroll
        for (int nt = 0; nt < 8; ++nt) {
            const int c = (nt << 4) + lj;
#pragma unroll
            for (int r = 0; r < 4; ++r) {
                const float mval = acc[mt][nt][r] * gate[mt][r];
                ap[nt] += mval;
                short h_, l_;
                bsplit(mval, h_, l_);
                const int j = (w << 5) + (mt << 4) + (g << 2) + r;
                const int idx = j * CC + (c ^ ((j & 7) << 3));
                ms[idx] = h_;
                llo[nt][r] = l_;
            }
        }
        const int jr = (w << 5) + (mt << 4) + lj;
#pragma unroll
        for (int kt = 0; kt < 4; ++kt) {
            const int ofs = jr * CC + ((((kt << 5) + (g << 3))) ^ ((jr & 7) << 3));
            a2h[mt][kt] = *reinterpret_cast<const s16x8*>(ms + ofs);
        }
#pragma unroll
        for (int nt = 0; nt < 8; ++nt) {
#pragma unroll
            for (int r = 0; r < 4; ++r) {
                const int j = (w << 5) + (mt << 4) + (g << 2) + r;
                const int idx = j * CC + ((((nt << 4) + lj)) ^ ((j & 7) << 3));
                ms[idx] = llo[nt][r];
            }
        }
#pragma unroll
        for (int kt = 0; kt < 4; ++kt) {
            const int ofs = jr * CC + ((((kt << 5) + (g << 3))) ^ ((jr & 7) << 3));
            a2l[mt][kt] = *reinterpret_cast<const s16x8*>(ms + ofs);
        }
    }
#pragma unroll
    for (int o = 16; o < 64; o <<= 1)
#pragma unroll
        for (int nt = 0; nt < 8; ++nt) ap[nt] += __shfl_xor(ap[nt], o, 64);
    if (g == 0) {
#pragma unroll
        for (int nt = 0; nt < 8; ++nt) aggp[(w << 7) + (nt << 4) + lj] = ap[nt];
    }
    __syncthreads();

    if (tid < 128) {
        agg[(size_t)n * CC + tid] =
            aggp[tid] + aggp[128 + tid] + aggp[256 + tid] + aggp[384 + tid];
    }

    // ---- gemm2: acc2 = m @ Wc1 (3-term split) -----------------------------
    f32x4 acc2[2][8];
#pragma unroll
    for (int mt = 0; mt < 2; ++mt)
#pragma unroll
        for (int nt = 0; nt < 8; ++nt) acc2[mt][nt] = (f32x4){0.f, 0.f, 0.f, 0.f};
#pragma unroll
    for (int kt = 0; kt < 4; ++kt) {
#pragma unroll
        for (int nt = 0; nt < 8; ++nt) {
            const int wo = ((nt << 4) + lj) * CC + (kt << 5) + (g << 3);
            const s16x8 bh = *reinterpret_cast<const s16x8*>(w2hiP + wo);
            const s16x8 bl = *reinterpret_cast<const s16x8*>(w2lo + wo);
#pragma unroll
            for (int mt = 0; mt < 2; ++mt) {
                acc2[mt][nt] = mfma16(a2h[mt][kt], bh, acc2[mt][nt]);
                acc2[mt][nt] = mfma16(a2h[mt][kt], bl, acc2[mt][nt]);
                acc2[mt][nt] = mfma16(a2l[mt][kt], bh, acc2[mt][nt]);
            }
        }
    }

    // ---- epilogue 2: silu(+bc1)*Wc2 -> tanh -> trans ----------------------
    float dt[2][4];
#pragma unroll
    for (int mt = 0; mt < 2; ++mt)
#pragma unroll
        for (int r = 0; r < 4; ++r) dt[mt][r] = 0.f;
#pragma unroll
    for (int mt = 0; mt < 2; ++mt)
#pragma unroll
        for (int nt = 0; nt < 8; ++nt) {
            const int c = (nt << 4) + lj;
            const float bc = bc1s[c], wc = wc2s[c];
#pragma unroll
            for (int r = 0; r < 4; ++r)
                dt[mt][r] = fmaf(fsilu(acc2[mt][nt][r] + bc), wc, dt[mt][r]);
        }
#pragma unroll
    for (int o = 1; o < 16; o <<= 1)
#pragma unroll
        for (int mt = 0; mt < 2; ++mt)
#pragma unroll
            for (int r = 0; r < 4; ++r) dt[mt][r] += __shfl_xor(dt[mt][r], o, 64);
    if (lj == 0) {
        float t0 = 0.f, t1 = 0.f, t2 = 0.f;
#pragma unroll
        for (int mt = 0; mt < 2; ++mt)
#pragma unroll
            for (int r = 0; r < 4; ++r) {
                const int j = (w << 5) + (mt << 4) + (g << 2) + r;
                const float ts = ftanh_(dt[mt][r]);
                t0 = fmaf(diffs[3 * j    ], ts, t0);
                t1 = fmaf(diffs[3 * j + 1], ts, t1);
                t2 = fmaf(diffs[3 * j + 2], ts, t2);
            }
        const int slot = (w << 2) + g;
        trp[slot * 4 + 0] = t0; trp[slot * 4 + 1] = t1; trp[slot * 4 + 2] = t2;
    }
    __syncthreads();
    if (tid < 3) {
        float s = 0.f;
#pragma unroll
        for (int q = 0; q < 16; ++q) s += trp[q * 4 + tid];
        xnext[3 * n + tid] = (xcur[3 * n + tid] + s) * mi;
    }
}

// ---------------------------------------------------------------- node ------
__global__ __launch_bounds__(128) void egnn_node(
    float* __restrict__ h, const float* __restrict__ agg,
    const float* __restrict__ nmask,
    const float* __restrict__ Wn1, const float* __restrict__ bn1,
    const float* __restrict__ Wn2, const float* __restrict__ bn2)
{
    __shared__ float hs[2][CC], as_[2][CC], hn[2][CC];
    const int c = threadIdx.x;
    const int n0 = blockIdx.x * 2;
    hs[0][c] = h[(size_t)n0 * CC + c];
    hs[1][c] = h[(size_t)(n0 + 1) * CC + c];
    as_[0][c] = agg[(size_t)n0 * CC + c];
    as_[1][c] = agg[(size_t)(n0 + 1) * CC + c];
    __syncthreads();
    float a0 = bn1[c], a1 = a0;
#pragma unroll 4
    for (int k = 0; k < CC; ++k) {
        const float wv = Wn1[k * CC + c];
        a0 = fmaf(hs[0][k], wv, a0); a1 = fmaf(hs[1][k], wv, a1);
    }
#pragma unroll 4
    for (int k = 0; k < CC; ++k) {
        const float wv = Wn1[(CC + k) * CC + c];
        a0 = fmaf(as_[0][k], wv, a0); a1 = fmaf(as_[1][k], wv, a1);
    }
    hn[0][c] = fsilu(a0); hn[1][c] = fsilu(a1);
    __syncthreads();
    a0 = bn2[c]; a1 = a0;
#pragma unroll 4
    for (int k = 0; k < CC; ++k) {
        const float wv = Wn2[k * CC + c];
        a0 = fmaf(hn[0][k], wv, a0); a1 = fmaf(hn[1][k], wv, a1);
    }
    h[(size_t)n0 * CC + c]       = (hs[0][c] + a0) * nmask[n0];
    h[(size_t)(n0 + 1) * CC + c] = (hs[1][c] + a1) * nmask[n0 + 1];
}

// ---------------------------------------------------------------- final -----
__global__ __launch_bounds__(128) void egnn_final(
    const float* __restrict__ xcur, const float* __restrict__ xf,
    const float* __restrict__ nmask, float* __restrict__ out)
{
    __shared__ float red[128][4];
    const int i = threadIdx.x, b = blockIdx.x;
    const int n = b * 128 + i;
    const float mi = nmask[n];
    const float v0 = (xcur[3 * n    ] - xf[3 * n    ]) * mi;
    const float v1 = (xcur[3 * n + 1] - xf[3 * n + 1]) * mi;
    const float v2 = (xcur[3 * n + 2] - xf[3 * n + 2]) * mi;
    red[i][0] = v0; red[i][1] = v1; red[i][2] = v2; red[i][3] = mi;
    __syncthreads();
    for (int s = 64; s > 0; s >>= 1) {
        if (i < s) {
            red[i][0] += red[i + s][0]; red[i][1] += red[i + s][1];
            red[i][2] += red[i + s][2]; red[i][3] += red[i + s][3];
        }
        __syncthreads();
    }
    const float inv = 1.0f / red[0][3];
    out[b * 384 + i * 3 + 0] = v0 - red[0][0] * inv * mi;
    out[b * 384 + i * 3 + 1] = v1 - red[0][1] * inv * mi;
    out[b * 384 + i * 3 + 2] = v2 - red[0][2] * inv * mi;
}

// ---------------------------------------------------------------- host ------
extern "C" void kernel_launch(void* const* d_in, const int* in_sizes, int n_in,
                              void* d_out, int out_size, void* d_ws, size_t ws_size,
                              hipStream_t stream) {
    const float* t     = (const float*)d_in[0];
    const float* x     = (const float*)d_in[1];
    const int*   atomt = (const int*)d_in[2];
    const int*   aapos = (const int*)d_in[3];
    const int*   aatyp = (const int*)d_in[4];
    const int*   slen  = (const int*)d_in[5];
    const float* nmask = (const float*)d_in[6];
    const float* embW  = (const float*)d_in[7];
    const float* embB  = (const float*)d_in[8];
    const float* We1   = (const float*)d_in[9];
    const float* be1   = (const float*)d_in[10];
    const float* We2   = (const float*)d_in[11];
    const float* be2   = (const float*)d_in[12];
    const float* Wa    = (const float*)d_in[13];
    const float* ba    = (const float*)d_in[14];
    const float* Wn1   = (const float*)d_in[15];
    const float* bn1   = (const float*)d_in[16];
    const float* Wn2   = (const float*)d_in[17];
    const float* bn2   = (const float*)d_in[18];
    const float* Wc1   = (const float*)d_in[19];
    const float* bc1   = (const float*)d_in[20];
    const float* Wc2   = (const float*)d_in[21];

    float* ws  = (float*)d_ws;
    float* h   = ws;                 // 2048*128
    float* P   = ws + 262144;        // 2048*128
    float* Q   = ws + 524288;        // 2048*128
    float* agg = ws + 786432;        // 2048*128
    float* xA  = ws + 1048576;       // 2048*3
    float* xB  = ws + 1054720;       // 2048*3
    float* xf  = ws + 1060864;       // 2048*3
    short* wt  = (short*)(ws + 1067008); // 6 mats * 32768 shorts = 384 KB
    float* out = (float*)d_out;

    egnn_init<<<2048, 128, 0, stream>>>(t, x, atomt, aapos, aatyp, slen, nmask,
                                        embW, embB, h, xf, xA);
    egnn_wtprep<<<96, 128, 0, stream>>>(We2, Wc1, wt);

    const size_t edge_lds = 16384 * sizeof(short) + 1664 * sizeof(float); // 39,424 B
    float* xc = xA;
    float* xn = xB;
    for (int l = 0; l < 3; ++l) {
        egnn_pq<<<1024, 128, 0, stream>>>(h, We1 + (size_t)l * 258 * CC,
                                          be1 + l * CC, P, Q);
        egnn_edge<<<2048, 256, edge_lds, stream>>>(
            P, Q, xc, xf, nmask,
            We1 + (size_t)l * 258 * CC + 256 * CC,   // rows 256,257: w_rad, w_ea
            wt + (size_t)(l * 2 + 0) * 32768,        // We2^T hi (lo at +16384)
            wt + (size_t)(l * 2 + 1) * 32768,        // Wc1^T hi (lo at +16384)
            be2 + l * CC, Wa + l * CC, ba + l, bc1 + l * CC, Wc2 + l * CC,
            xn, agg);
        if (l < 2) {
            // node h-update for l==2 is dead (h never read again; output
            // depends only on the coordinate stream) -> skip the launch.
            egnn_node<<<1024, 128, 0, stream>>>(h, agg, nmask,
                                                Wn1 + (size_t)l * 2 * CC * CC, bn1 + l * CC,
                                                Wn2 + (size_t)l * CC * CC, bn2 + l * CC);
        }
        float* tmp = xc; xc = xn; xn = tmp;
    }
    egnn_final<<<16, 128, 0, stream>>>(xc, xf, nmask, out);
}

// Round 13
// 679.920 us; speedup vs baseline: 1.2305x; 1.2305x over previous
//
#include <hip/hip_runtime.h>
#include <math.h>

#define CC 128   // channels
// B=16, N=128 per graph, BN=2048 nodes, L=3 layers
// Edge kernel: MFMA split-bf16 (3-term), two-pass wave-local m staging
// (one 32KB LDS plane time-shared hi->lo) -> 39,424 B LDS.
// launch_bounds(256,2): (256,4) forced VGPR 128->64 -> ~1KB/thread scratch
// spills -> 561 MB HBM/dispatch, 227us (round-12 regression). (256,2) gave
// VGPR=128 no-spill (round 10); with 39.4KB LDS that allows 4 blocks/CU.

typedef float  f32x4  __attribute__((ext_vector_type(4)));
typedef short  s16x8  __attribute__((ext_vector_type(8)));
typedef __bf16 bf16x8 __attribute__((ext_vector_type(8)));

__device__ __forceinline__ float fsilu(float x) { return x / (1.0f + __expf(-x)); }
__device__ __forceinline__ float fsigm(float x) { return 1.0f / (1.0f + __expf(-x)); }
__device__ __forceinline__ float ftanh_(float x) { return 1.0f - 2.0f / (__expf(2.0f * x) + 1.0f); }

// Split fp32 -> bf16 hi + bf16 lo (RNE both). x ~= hi + lo with ~2^-16 rel err.
__device__ __forceinline__ void bsplit(float x, short& hi, short& lo) {
    unsigned xu = __float_as_uint(x);
    unsigned hr = (xu + 0x7FFFu + ((xu >> 16) & 1u)) & 0xFFFF0000u;
    float hf = __uint_as_float(hr);
    float r = x - hf;
    unsigned ru = __float_as_uint(r);
    unsigned lr = ru + 0x7FFFu + ((ru >> 16) & 1u);
    hi = (short)(hr >> 16);
    lo = (short)(lr >> 16);
}

__device__ __forceinline__ f32x4 mfma16(s16x8 a, s16x8 b, f32x4 c) {
    return __builtin_amdgcn_mfma_f32_16x16x32_bf16(
        __builtin_bit_cast(bf16x8, a), __builtin_bit_cast(bf16x8, b), c, 0, 0, 0);
}

// ---------------------------------------------------------------- init ------
__global__ __launch_bounds__(128) void egnn_init(
    const float* __restrict__ t, const float* __restrict__ x,
    const int* __restrict__ atomt, const int* __restrict__ aapos,
    const int* __restrict__ aatype, const int* __restrict__ slen,
    const float* __restrict__ nmask, const float* __restrict__ embW,
    const float* __restrict__ embB, float* __restrict__ h,
    float* __restrict__ xf, float* __restrict__ xA)
{
    const int n = blockIdx.x;
    const int c = threadIdx.x;
    const int b = n >> 7;
    const int i = n & 127;
    const float mi = nmask[n];
    int ia = atomt[n] - 1; if (ia < 0) ia = 0;
    int ip = aapos[n] - 1; if (ip < 0) ip = 0;
    int iq = aatype[n] - 1; if (iq < 0) iq = 0;
    int is = slen[b] - 5;  if (is < 0) is = 0;
    const float tt = t[b] * mi;
    float v = mi * (embW[ia * CC + c] + embW[(54 + ip) * CC + c] +
                    embW[(84 + iq) * CC + c] + embW[(104 + is) * CC + c]) +
              tt * embW[130 * CC + c] + embB[c];
    h[(size_t)n * CC + c] = v;
    if (c < 3) {
        float xv = x[b * 384 + i * 3 + c] * mi;
        xf[3 * n + c] = xv;
        xA[3 * n + c] = xv;
    }
}

// ------------------------------------------------------- weight prep --------
__global__ __launch_bounds__(128) void egnn_wtprep(
    const float* __restrict__ We2, const float* __restrict__ Wc1,
    short* __restrict__ wt)
{
    const int blk = blockIdx.x;          // 96 = 3 layers x 2 mats x 16 chunks
    const int l = blk >> 5;
    const int mat = (blk >> 4) & 1;
    const int chunk = blk & 15;
    const int k = threadIdx.x;
    const float* W = (mat == 0 ? We2 : Wc1) + (size_t)l * CC * CC;
    short* hi = wt + (size_t)(l * 2 + mat) * 32768;
    short* lo = hi + 16384;
#pragma unroll
    for (int nn = 0; nn < 8; ++nn) {
        const int n = chunk * 8 + nn;
        short h_, l_;
        bsplit(W[k * CC + n], h_, l_);
        hi[n * CC + k] = h_;
        lo[n * CC + k] = l_;
    }
}

// ---------------------------------------------------------------- P,Q -------
__global__ __launch_bounds__(128) void egnn_pq(
    const float* __restrict__ h, const float* __restrict__ We1,
    const float* __restrict__ be1, float* __restrict__ P, float* __restrict__ Q)
{
    __shared__ float hs[2][CC];
    const int c = threadIdx.x;
    const int n0 = blockIdx.x * 2;
    hs[0][c] = h[(size_t)n0 * CC + c];
    hs[1][c] = h[(size_t)(n0 + 1) * CC + c];
    __syncthreads();
    const float bv = be1[c];
    float p0 = bv, p1 = bv, q0 = 0.f, q1 = 0.f;
#pragma unroll 4
    for (int k = 0; k < CC; ++k) {
        const float wr = We1[k * CC + c];
        const float wc = We1[(CC + k) * CC + c];
        p0 = fmaf(hs[0][k], wr, p0); p1 = fmaf(hs[1][k], wr, p1);
        q0 = fmaf(hs[0][k], wc, q0); q1 = fmaf(hs[1][k], wc, q1);
    }
    P[(size_t)n0 * CC + c] = p0; P[(size_t)(n0 + 1) * CC + c] = p1;
    Q[(size_t)n0 * CC + c] = q0; Q[(size_t)(n0 + 1) * CC + c] = q1;
}

// ---------------------------------------------------------------- edge ------
// One block per (graph b, row i): 128 edges (i,j). 256 thr = 4 waves.
// Wave w owns j-strip [32w, 32w+32). LDS: one 32KB m-plane (two-pass hi/lo,
// wave-local rows -> no barrier) + 6.5KB floats with phase-A consts overlaid
// by aggp/trp (guarded by one barrier after phase A).
__global__ __launch_bounds__(256, 2) void egnn_edge(
    const float* __restrict__ P, const float* __restrict__ Q,
    const float* __restrict__ xcur, const float* __restrict__ xf,
    const float* __restrict__ nmask, const float* __restrict__ We1t,
    const short* __restrict__ w1hiP, const short* __restrict__ w2hiP,
    const float* __restrict__ be2, const float* __restrict__ Wa,
    const float* __restrict__ ba, const float* __restrict__ bc1,
    const float* __restrict__ Wc2,
    float* __restrict__ xnext, float* __restrict__ agg)
{
    extern __shared__ char smraw[];
    short* ms    = (short*)smraw;         // 128x128 shorts (swizzled), 32KB
    float* fb    = (float*)(ms + 16384);
    float* diffs = fb;                    // 384  (live whole kernel)
    float* emks  = fb + 384;              // 128  (live: ep1)
    float* wass  = fb + 512;              // 128
    float* wc2s  = fb + 640;              // 128
    float* be2s  = fb + 768;              // 128
    float* bc1s  = fb + 896;              // 128
    float* ovl   = fb + 1024;             // 640-float overlay region
    float* rjs   = ovl;                   // 128 (phase A only)
    float* eas   = ovl + 128;             // 128 (phase A only)
    float* pis   = ovl + 256;             // 128 (phase A only)
    float* wrads = ovl + 384;             // 128 (phase A only)
    float* weas  = ovl + 512;             // 128 (phase A only)
    float* aggp  = ovl;                   // 512 (after phase-A barrier)
    float* trp   = ovl + 512;             // 64  (after phase-A barrier)
    // total 32768 + 1664*4 = 39,424 B -> 4 blocks/CU (LDS-wise)

    const int tid = threadIdx.x;
    const int w  = tid >> 6;
    const int lane = tid & 63;
    const int g  = lane >> 4;            // 0..3
    const int lj = lane & 15;            // 0..15
    const int n = blockIdx.x;
    const int b = n >> 7;
    const int i = n & 127;
    const int nb = b << 7;
    const float mi = nmask[n];

    const short* w1lo = w1hiP + 16384;
    const short* w2lo = w2hiP + 16384;

    if (tid < 128) {
        const int j = tid;
        const float xi0 = xcur[3 * n], xi1 = xcur[3 * n + 1], xi2 = xcur[3 * n + 2];
        const float xj0 = xcur[3 * (nb + j)], xj1 = xcur[3 * (nb + j) + 1], xj2 = xcur[3 * (nb + j) + 2];
        const float d0 = xi0 - xj0, d1 = xi1 - xj1, d2 = xi2 - xj2;
        diffs[3 * j] = d0; diffs[3 * j + 1] = d1; diffs[3 * j + 2] = d2;
        rjs[j] = d0 * d0 + d1 * d1 + d2 * d2;
        const float f0 = xf[3 * n] - xf[3 * (nb + j)];
        const float f1 = xf[3 * n + 1] - xf[3 * (nb + j) + 1];
        const float f2 = xf[3 * n + 2] - xf[3 * (nb + j) + 2];
        eas[j] = f0 * f0 + f1 * f1 + f2 * f2;
        emks[j] = mi * nmask[nb + j] * ((j == i) ? 0.0f : 1.0f);
    } else {
        const int c = tid - 128;
        pis[c]   = P[(size_t)n * CC + c];
        wrads[c] = We1t[c];
        weas[c]  = We1t[CC + c];
        wass[c]  = Wa[c];
        wc2s[c]  = Wc2[c];
        be2s[c]  = be2[c];
        bc1s[c]  = bc1[c];
    }
    __syncthreads();

    // ---- Phase A: M1 computed directly into A-fragment registers ----------
    s16x8 ahi[2][4], alo[2][4];
#pragma unroll
    for (int mt = 0; mt < 2; ++mt) {
        const int j = (w << 5) + (mt << 4) + lj;
        const float r  = rjs[j];
        const float ea = eas[j];
        const float* Qj = Q + (size_t)(nb + j) * CC;
#pragma unroll
        for (int kt = 0; kt < 4; ++kt) {
            const int c0 = (kt << 5) + (g << 3);
            const float4 q0 = *reinterpret_cast<const float4*>(Qj + c0);
            const float4 q1 = *reinterpret_cast<const float4*>(Qj + c0 + 4);
            const float4 p0 = *reinterpret_cast<const float4*>(pis + c0);
            const float4 p1 = *reinterpret_cast<const float4*>(pis + c0 + 4);
            const float4 r0 = *reinterpret_cast<const float4*>(wrads + c0);
            const float4 r1 = *reinterpret_cast<const float4*>(wrads + c0 + 4);
            const float4 e0 = *reinterpret_cast<const float4*>(weas + c0);
            const float4 e1 = *reinterpret_cast<const float4*>(weas + c0 + 4);
            float vv[8];
            vv[0] = fsilu(p0.x + q0.x + r * r0.x + ea * e0.x);
            vv[1] = fsilu(p0.y + q0.y + r * r0.y + ea * e0.y);
            vv[2] = fsilu(p0.z + q0.z + r * r0.z + ea * e0.z);
            vv[3] = fsilu(p0.w + q0.w + r * r0.w + ea * e0.w);
            vv[4] = fsilu(p1.x + q1.x + r * r1.x + ea * e1.x);
            vv[5] = fsilu(p1.y + q1.y + r * r1.y + ea * e1.y);
            vv[6] = fsilu(p1.z + q1.z + r * r1.z + ea * e1.z);
            vv[7] = fsilu(p1.w + q1.w + r * r1.w + ea * e1.w);
#pragma unroll
            for (int e = 0; e < 8; ++e) {
                short h_, l_;
                bsplit(vv[e], h_, l_);
                ahi[mt][kt][e] = h_;
                alo[mt][kt][e] = l_;
            }
        }
    }
    // Overlay guard: all phase-A reads of rjs/eas/pis/wrads/weas are done in
    // every wave before any wave writes aggp/trp (same LDS words).
    __syncthreads();

    // ---- gemm1: acc[mt][nt] = M1 @ We2 (3-term split) ---------------------
    f32x4 acc[2][8];
#pragma unroll
    for (int mt = 0; mt < 2; ++mt)
#pragma unroll
        for (int nt = 0; nt < 8; ++nt) acc[mt][nt] = (f32x4){0.f, 0.f, 0.f, 0.f};
#pragma unroll
    for (int kt = 0; kt < 4; ++kt) {
#pragma unroll
        for (int nt = 0; nt < 8; ++nt) {
            const int wo = ((nt << 4) + lj) * CC + (kt << 5) + (g << 3);
            const s16x8 bh = *reinterpret_cast<const s16x8*>(w1hiP + wo);
            const s16x8 bl = *reinterpret_cast<const s16x8*>(w1lo + wo);
#pragma unroll
            for (int mt = 0; mt < 2; ++mt) {
                acc[mt][nt] = mfma16(ahi[mt][kt], bh, acc[mt][nt]);
                acc[mt][nt] = mfma16(ahi[mt][kt], bl, acc[mt][nt]);
                acc[mt][nt] = mfma16(alo[mt][kt], bh, acc[mt][nt]);
            }
        }
    }

    // ---- epilogue 1: silu + attention gate + agg partials -----------------
    // D-frag: row j = 32w+16mt+4g+r, col c = 16nt+lj.
    float pa[2][4];
#pragma unroll
    for (int mt = 0; mt < 2; ++mt)
#pragma unroll
        for (int r = 0; r < 4; ++r) pa[mt][r] = 0.f;
#pragma unroll
    for (int mt = 0; mt < 2; ++mt)
#pragma unroll
        for (int nt = 0; nt < 8; ++nt) {
            const int c = (nt << 4) + lj;
            const float be = be2s[c], wa = wass[c];
#pragma unroll
            for (int r = 0; r < 4; ++r) {
                const float v = fsilu(acc[mt][nt][r] + be);
                acc[mt][nt][r] = v;
                pa[mt][r] = fmaf(v, wa, pa[mt][r]);
            }
        }
#pragma unroll
    for (int o = 1; o < 16; o <<= 1)
#pragma unroll
        for (int mt = 0; mt < 2; ++mt)
#pragma unroll
            for (int r = 0; r < 4; ++r) pa[mt][r] += __shfl_xor(pa[mt][r], o, 64);
    const float bav = ba[0];
    float gate[2][4];
#pragma unroll
    for (int mt = 0; mt < 2; ++mt)
#pragma unroll
        for (int r = 0; r < 4; ++r) {
            const int j = (w << 5) + (mt << 4) + (g << 2) + r;
            gate[mt][r] = fsigm(pa[mt][r] + bav) * emks[j];
        }

    // ---- two-pass wave-local m staging + gemm2 A-fragment loads -----------
    // Per m-tile: write hi -> read a2h -> write lo (same words) -> read a2l.
    // Rows are wave-private; intra-wave LDS dependency ordering suffices.
    float ap[8];
#pragma unroll
    for (int nt = 0; nt < 8; ++nt) ap[nt] = 0.f;
    s16x8 a2h[2][4], a2l[2][4];
#pragma unroll
    for (int mt = 0; mt < 2; ++mt) {
        short llo[8][4];
#pragma unroll
        for (int nt = 0; nt < 8; ++nt) {
            const int c = (nt << 4) + lj;
#pragma unroll
            for (int r = 0; r < 4; ++r) {
                const float mval = acc[mt][nt][r] * gate[mt][r];
                ap[nt] += mval;
                short h_, l_;
                bsplit(mval, h_, l_);
                const int j = (w << 5) + (mt << 4) + (g << 2) + r;
                const int idx = j * CC + (c ^ ((j & 7) << 3));
                ms[idx] = h_;
                llo[nt][r] = l_;
            }
        }
        const int jr = (w << 5) + (mt << 4) + lj;
#pragma unroll
        for (int kt = 0; kt < 4; ++kt) {
            const int ofs = jr * CC + ((((kt << 5) + (g << 3))) ^ ((jr & 7) << 3));
            a2h[mt][kt] = *reinterpret_cast<const s16x8*>(ms + ofs);
        }
#pragma unroll
        for (int nt = 0; nt < 8; ++nt) {
#pragma unroll
            for (int r = 0; r < 4; ++r) {
                const int j = (w << 5) + (mt << 4) + (g << 2) + r;
                const int idx = j * CC + ((((nt << 4) + lj)) ^ ((j & 7) << 3));
                ms[idx] = llo[nt][r];
            }
        }
#pragma unroll
        for (int kt = 0; kt < 4; ++kt) {
            const int ofs = jr * CC + ((((kt << 5) + (g << 3))) ^ ((jr & 7) << 3));
            a2l[mt][kt] = *reinterpret_cast<const s16x8*>(ms + ofs);
        }
    }
#pragma unroll
    for (int o = 16; o < 64; o <<= 1)
#pragma unroll
        for (int nt = 0; nt < 8; ++nt) ap[nt] += __shfl_xor(ap[nt], o, 64);
    if (g == 0) {
#pragma unroll
        for (int nt = 0; nt < 8; ++nt) aggp[(w << 7) + (nt << 4) + lj] = ap[nt];
    }
    __syncthreads();

    if (tid < 128) {
        agg[(size_t)n * CC + tid] =
            aggp[tid] + aggp[128 + tid] + aggp[256 + tid] + aggp[384 + tid];
    }

    // ---- gemm2: acc2 = m @ Wc1 (3-term split) -----------------------------
    f32x4 acc2[2][8];
#pragma unroll
    for (int mt = 0; mt < 2; ++mt)
#pragma unroll
        for (int nt = 0; nt < 8; ++nt) acc2[mt][nt] = (f32x4){0.f, 0.f, 0.f, 0.f};
#pragma unroll
    for (int kt = 0; kt < 4; ++kt) {
#pragma unroll
        for (int nt = 0; nt < 8; ++nt) {
            const int wo = ((nt << 4) + lj) * CC + (kt << 5) + (g << 3);
            const s16x8 bh = *reinterpret_cast<const s16x8*>(w2hiP + wo);
            const s16x8 bl = *reinterpret_cast<const s16x8*>(w2lo + wo);
#pragma unroll
            for (int mt = 0; mt < 2; ++mt) {
                acc2[mt][nt] = mfma16(a2h[mt][kt], bh, acc2[mt][nt]);
                acc2[mt][nt] = mfma16(a2h[mt][kt], bl, acc2[mt][nt]);
                acc2[mt][nt] = mfma16(a2l[mt][kt], bh, acc2[mt][nt]);
            }
        }
    }

    // ---- epilogue 2: silu(+bc1)*Wc2 -> tanh -> trans ----------------------
    float dt[2][4];
#pragma unroll
    for (int mt = 0; mt < 2; ++mt)
#pragma unroll
        for (int r = 0; r < 4; ++r) dt[mt][r] = 0.f;
#pragma unroll
    for (int mt = 0; mt < 2; ++mt)
#pragma unroll
        for (int nt = 0; nt < 8; ++nt) {
            const int c = (nt << 4) + lj;
            const float bc = bc1s[c], wc = wc2s[c];
#pragma unroll
            for (int r = 0; r < 4; ++r)
                dt[mt][r] = fmaf(fsilu(acc2[mt][nt][r] + bc), wc, dt[mt][r]);
        }
#pragma unroll
    for (int o = 1; o < 16; o <<= 1)
#pragma unroll
        for (int mt = 0; mt < 2; ++mt)
#pragma unroll
            for (int r = 0; r < 4; ++r) dt[mt][r] += __shfl_xor(dt[mt][r], o, 64);
    if (lj == 0) {
        float t0 = 0.f, t1 = 0.f, t2 = 0.f;
#pragma unroll
        for (int mt = 0; mt < 2; ++mt)
#pragma unroll
            for (int r = 0; r < 4; ++r) {
                const int j = (w << 5) + (mt << 4) + (g << 2) + r;
                const float ts = ftanh_(dt[mt][r]);
                t0 = fmaf(diffs[3 * j    ], ts, t0);
                t1 = fmaf(diffs[3 * j + 1], ts, t1);
                t2 = fmaf(diffs[3 * j + 2], ts, t2);
            }
        const int slot = (w << 2) + g;
        trp[slot * 4 + 0] = t0; trp[slot * 4 + 1] = t1; trp[slot * 4 + 2] = t2;
    }
    __syncthreads();
    if (tid < 3) {
        float s = 0.f;
#pragma unroll
        for (int q = 0; q < 16; ++q) s += trp[q * 4 + tid];
        xnext[3 * n + tid] = (xcur[3 * n + tid] + s) * mi;
    }
}

// ---------------------------------------------------------------- node ------
__global__ __launch_bounds__(128) void egnn_node(
    float* __restrict__ h, const float* __restrict__ agg,
    const float* __restrict__ nmask,
    const float* __restrict__ Wn1, const float* __restrict__ bn1,
    const float* __restrict__ Wn2, const float* __restrict__ bn2)
{
    __shared__ float hs[2][CC], as_[2][CC], hn[2][CC];
    const int c = threadIdx.x;
    const int n0 = blockIdx.x * 2;
    hs[0][c] = h[(size_t)n0 * CC + c];
    hs[1][c] = h[(size_t)(n0 + 1) * CC + c];
    as_[0][c] = agg[(size_t)n0 * CC + c];
    as_[1][c] = agg[(size_t)(n0 + 1) * CC + c];
    __syncthreads();
    float a0 = bn1[c], a1 = a0;
#pragma unroll 4
    for (int k = 0; k < CC; ++k) {
        const float wv = Wn1[k * CC + c];
        a0 = fmaf(hs[0][k], wv, a0); a1 = fmaf(hs[1][k], wv, a1);
    }
#pragma unroll 4
    for (int k = 0; k < CC; ++k) {
        const float wv = Wn1[(CC + k) * CC + c];
        a0 = fmaf(as_[0][k], wv, a0); a1 = fmaf(as_[1][k], wv, a1);
    }
    hn[0][c] = fsilu(a0); hn[1][c] = fsilu(a1);
    __syncthreads();
    a0 = bn2[c]; a1 = a0;
#pragma unroll 4
    for (int k = 0; k < CC; ++k) {
        const float wv = Wn2[k * CC + c];
        a0 = fmaf(hn[0][k], wv, a0); a1 = fmaf(hn[1][k], wv, a1);
    }
    h[(size_t)n0 * CC + c]       = (hs[0][c] + a0) * nmask[n0];
    h[(size_t)(n0 + 1) * CC + c] = (hs[1][c] + a1) * nmask[n0 + 1];
}

// ---------------------------------------------------------------- final -----
__global__ __launch_bounds__(128) void egnn_final(
    const float* __restrict__ xcur, const float* __restrict__ xf,
    const float* __restrict__ nmask, float* __restrict__ out)
{
    __shared__ float red[128][4];
    const int i = threadIdx.x, b = blockIdx.x;
    const int n = b * 128 + i;
    const float mi = nmask[n];
    const float v0 = (xcur[3 * n    ] - xf[3 * n    ]) * mi;
    const float v1 = (xcur[3 * n + 1] - xf[3 * n + 1]) * mi;
    const float v2 = (xcur[3 * n + 2] - xf[3 * n + 2]) * mi;
    red[i][0] = v0; red[i][1] = v1; red[i][2] = v2; red[i][3] = mi;
    __syncthreads();
    for (int s = 64; s > 0; s >>= 1) {
        if (i < s) {
            red[i][0] += red[i + s][0]; red[i][1] += red[i + s][1];
            red[i][2] += red[i + s][2]; red[i][3] += red[i + s][3];
        }
        __syncthreads();
    }
    const float inv = 1.0f / red[0][3];
    out[b * 384 + i * 3 + 0] = v0 - red[0][0] * inv * mi;
    out[b * 384 + i * 3 + 1] = v1 - red[0][1] * inv * mi;
    out[b * 384 + i * 3 + 2] = v2 - red[0][2] * inv * mi;
}

// ---------------------------------------------------------------- host ------
extern "C" void kernel_launch(void* const* d_in, const int* in_sizes, int n_in,
                              void* d_out, int out_size, void* d_ws, size_t ws_size,
                              hipStream_t stream) {
    const float* t     = (const float*)d_in[0];
    const float* x     = (const float*)d_in[1];
    const int*   atomt = (const int*)d_in[2];
    const int*   aapos = (const int*)d_in[3];
    const int*   aatyp = (const int*)d_in[4];
    const int*   slen  = (const int*)d_in[5];
    const float* nmask = (const float*)d_in[6];
    const float* embW  = (const float*)d_in[7];
    const float* embB  = (const float*)d_in[8];
    const float* We1   = (const float*)d_in[9];
    const float* be1   = (const float*)d_in[10];
    const float* We2   = (const float*)d_in[11];
    const float* be2   = (const float*)d_in[12];
    const float* Wa    = (const float*)d_in[13];
    const float* ba    = (const float*)d_in[14];
    const float* Wn1   = (const float*)d_in[15];
    const float* bn1   = (const float*)d_in[16];
    const float* Wn2   = (const float*)d_in[17];
    const float* bn2   = (const float*)d_in[18];
    const float* Wc1   = (const float*)d_in[19];
    const float* bc1   = (const float*)d_in[20];
    const float* Wc2   = (const float*)d_in[21];

    float* ws  = (float*)d_ws;
    float* h   = ws;                 // 2048*128
    float* P   = ws + 262144;        // 2048*128
    float* Q   = ws + 524288;        // 2048*128
    float* agg = ws + 786432;        // 2048*128
    float* xA  = ws + 1048576;       // 2048*3
    float* xB  = ws + 1054720;       // 2048*3
    float* xf  = ws + 1060864;       // 2048*3
    short* wt  = (short*)(ws + 1067008); // 6 mats * 32768 shorts = 384 KB
    float* out = (float*)d_out;

    egnn_init<<<2048, 128, 0, stream>>>(t, x, atomt, aapos, aatyp, slen, nmask,
                                        embW, embB, h, xf, xA);
    egnn_wtprep<<<96, 128, 0, stream>>>(We2, Wc1, wt);

    const size_t edge_lds = 16384 * sizeof(short) + 1664 * sizeof(float); // 39,424 B
    float* xc = xA;
    float* xn = xB;
    for (int l = 0; l < 3; ++l) {
        egnn_pq<<<1024, 128, 0, stream>>>(h, We1 + (size_t)l * 258 * CC,
                                          be1 + l * CC, P, Q);
        egnn_edge<<<2048, 256, edge_lds, stream>>>(
            P, Q, xc, xf, nmask,
            We1 + (size_t)l * 258 * CC + 256 * CC,   // rows 256,257: w_rad, w_ea
            wt + (size_t)(l * 2 + 0) * 32768,        // We2^T hi (lo at +16384)
            wt + (size_t)(l * 2 + 1) * 32768,        // Wc1^T hi (lo at +16384)
            be2 + l * CC, Wa + l * CC, ba + l, bc1 + l * CC, Wc2 + l * CC,
            xn, agg);
        if (l < 2) {
            // node h-update for l==2 is dead (h never read again; output
            // depends only on the coordinate stream) -> skip the launch.
            egnn_node<<<1024, 128, 0, stream>>>(h, agg, nmask,
                                                Wn1 + (size_t)l * 2 * CC * CC, bn1 + l * CC,
                                                Wn2 + (size_t)l * CC * CC, bn2 + l * CC);
        }
        float* tmp = xc; xc = xn; xn = tmp;
    }
    egnn_final<<<16, 128, 0, stream>>>(xc, xf, nmask, out);
}